// Round 1
// baseline (12134.329 us; speedup 1.0000x reference)
//
#include <hip/hip_runtime.h>
#include <math.h>

// ---------------- problem constants ----------------
#define TILE 16
#define NTHR 256
#define N_ROWS 80000
// LDS pitches (floats), padded to dodge 32-bank power-of-2 strides
#define P_XS  484   // x tile row pitch (480 data)
#define P_CAT 164   // concat [s_k(128) | n_k(32) | p0(1) | pad]
#define P_V   196   // v_k / v_prev (192 data, j*3+m layout)
#define P_SK  260   // S_k (256)
#define P_V1O 196   // v1o (192)
#define P_SCR 196   // scratch / reductions
#define P_MB  132   // m (128)
#define P_N0  260   // Num0 (256)
#define P_N1  388   // Num1 (384)
#define P_ST  12    // per-row state: p0,p1[3],|p1|,mu,rstd,e,Z,mx,w,rf

#define SMEM_FLOATS (TILE*(P_XS+P_CAT+2*P_V+P_SK+P_V1O+P_SCR+P_MB+P_N0+P_N1+P_ST))
#define SMEM_BYTES (SMEM_FLOATS*4)

__device__ __forceinline__ float sigmoidf_(float x) { return 1.f/(1.f+expf(-x)); }

__global__ __launch_bounds__(NTHR, 1)
void efb_kernel(const float* __restrict__ x0, const float* __restrict__ x1,
                const float* __restrict__ x2, const float* __restrict__ x3,
                const float* __restrict__ Wl0, const float* __restrict__ Wl1,
                const float* __restrict__ Wl2, const float* __restrict__ Wtp0,
                const float* __restrict__ Wtp1, const float* __restrict__ Wsm,
                const float* __restrict__ bsv, const float* __restrict__ Wv1o,
                const float* __restrict__ Wv1e, const float* __restrict__ gma,
                const float* __restrict__ bta, const float* __restrict__ Wm1,
                const float* __restrict__ bm1, const float* __restrict__ Wm2,
                const float* __restrict__ bm2, float* __restrict__ out)
{
  extern __shared__ float smem[];
  float* xs  = smem;                  // TILE*P_XS
  float* cat = xs  + TILE*P_XS;
  float* vb0 = cat + TILE*P_CAT;
  float* vb1 = vb0 + TILE*P_V;
  float* Sk  = vb1 + TILE*P_V;
  float* v1o = Sk  + TILE*P_SK;
  float* scr = v1o + TILE*P_V1O;
  float* mb  = scr + TILE*P_SCR;
  float* Nm0 = mb  + TILE*P_MB;
  float* Nm1 = Nm0 + TILE*P_N0;
  float* st  = Nm1 + TILE*P_N1;

  const int tid  = threadIdx.x;
  const int row0 = blockIdx.x * TILE;
  const float* xptr[4] = {x0, x1, x2, x3};

  const float INV0 = 0.08838834764831845f;   // 1/sqrt(128)
  const float INV1 = 0.125f;                 // 1/sqrt(64)
  const float INV2 = 0.17677669529663687f;   // 1/sqrt(32)
  const float P0S  = 0.009021097956087907f;  // 1/(sqrt(3)*64)
  const float P1S  = 0.011048543456039806f;  // 1/(sqrt(2)*64)

  const int j0 = tid & 63;   // 64 feature lanes
  const int rg = tid >> 6;   // 4 row groups of 4 rows

  for (int k = 0; k < 4; ++k) {
    float* vcur  = (k & 1) ? vb1 : vb0;
    float* vprev = (k & 1) ? vb0 : vb1;

    // ---- A: stage x tile (coalesced float4) ----
    {
      const float4* xv = reinterpret_cast<const float4*>(xptr[k] + (size_t)row0 * 480);
      for (int idx = tid; idx < TILE * 120; idx += NTHR) {
        int r = idx / 120, c = idx - r * 120;
        float4 v = xv[idx];
        *reinterpret_cast<float4*>(&xs[r * P_XS + c * 4]) = v;
      }
    }
    __syncthreads();

    // ---- B: s_k = x_s @ Wl0[k] * inv0  -> cat[:,0:128] ----
    {
      const float* W = Wl0 + k * 128 * 128;
      float a0[4] = {0,0,0,0}, a1[4] = {0,0,0,0};
      #pragma unroll 4
      for (int i = 0; i < 128; ++i) {
        float w0 = W[i * 128 + j0];
        float w1 = W[i * 128 + j0 + 64];
        #pragma unroll
        for (int rr = 0; rr < 4; ++rr) {
          float a = xs[(rg * 4 + rr) * P_XS + i];
          a0[rr] = fmaf(a, w0, a0[rr]);
          a1[rr] = fmaf(a, w1, a1[rr]);
        }
      }
      #pragma unroll
      for (int rr = 0; rr < 4; ++rr) {
        cat[(rg * 4 + rr) * P_CAT + j0]      = a0[rr] * INV0;
        cat[(rg * 4 + rr) * P_CAT + j0 + 64] = a1[rr] * INV0;
      }
    }

    // ---- C: v_k[j][m] = sum_i x_v[i][m] Wl1[i][j] * inv1 ----
    {
      const float* W = Wl1 + k * 64 * 64;
      float ac[3][4] = {};
      #pragma unroll 2
      for (int i = 0; i < 64; ++i) {
        float w = W[i * 64 + j0];
        #pragma unroll
        for (int m = 0; m < 3; ++m)
          #pragma unroll
          for (int rr = 0; rr < 4; ++rr) {
            float a = xs[(rg * 4 + rr) * P_XS + 128 + i * 3 + m];
            ac[m][rr] = fmaf(a, w, ac[m][rr]);
          }
      }
      #pragma unroll
      for (int rr = 0; rr < 4; ++rr)
        #pragma unroll
        for (int m = 0; m < 3; ++m)
          vcur[(rg * 4 + rr) * P_V + j0 * 3 + m] = ac[m][rr] * INV1;
    }

    // ---- D: T_k then n_k -> cat[:,128:160]; zero cat[:,160:164] ----
    {
      const int j2 = tid & 31, rg2 = tid >> 5;  // 8 groups x 2 rows
      const float* W = Wl2 + k * 32 * 32;
      float ac[5][2] = {};
      #pragma unroll 2
      for (int i = 0; i < 32; ++i) {
        float w = W[i * 32 + j2];
        #pragma unroll
        for (int m = 0; m < 5; ++m)
          #pragma unroll
          for (int rr = 0; rr < 2; ++rr) {
            float a = xs[(rg2 * 2 + rr) * P_XS + 320 + i * 5 + m];
            ac[m][rr] = fmaf(a, w, ac[m][rr]);
          }
      }
      #pragma unroll
      for (int rr = 0; rr < 2; ++rr) {
        float s = 0.f;
        #pragma unroll
        for (int m = 0; m < 5; ++m) { float t = ac[m][rr] * INV2; s = fmaf(t, t, s); }
        cat[(rg2 * 2 + rr) * P_CAT + 128 + j2] = sqrtf(s);
      }
      if (tid < 64) cat[(tid >> 2) * P_CAT + 160 + (tid & 3)] = 0.f;
    }
    __syncthreads();

    // ---- E: p0, p1 (k>0) ----
    if (k > 0) {
      { // u0 = v_k . Wtp0 ; partial p0 = sum_m u0[j][m]*v_prev[j][m]
        float ac[3][4] = {};
        #pragma unroll 2
        for (int i = 0; i < 64; ++i) {
          float w = Wtp0[i * 64 + j0];
          #pragma unroll
          for (int m = 0; m < 3; ++m)
            #pragma unroll
            for (int rr = 0; rr < 4; ++rr)
              ac[m][rr] = fmaf(vcur[(rg * 4 + rr) * P_V + i * 3 + m], w, ac[m][rr]);
        }
        #pragma unroll
        for (int rr = 0; rr < 4; ++rr) {
          int r = rg * 4 + rr;
          float s = 0.f;
          #pragma unroll
          for (int m = 0; m < 3; ++m) s = fmaf(ac[m][rr], vprev[r * P_V + j0 * 3 + m], s);
          scr[r * P_SCR + j0] = s;
        }
      }
      __syncthreads();
      if (tid < TILE) {
        float s = 0.f;
        for (int j = 0; j < 64; ++j) s += scr[tid * P_SCR + j];
        float p0v = s * P0S;
        st[tid * P_ST + 0] = p0v;
        cat[tid * P_CAT + 160] = p0v;
      }
      __syncthreads();
      { // u1 = v_k . Wtp1 ; cross(u1, v_prev) partials
        float ac[3][4] = {};
        #pragma unroll 2
        for (int i = 0; i < 64; ++i) {
          float w = Wtp1[i * 64 + j0];
          #pragma unroll
          for (int m = 0; m < 3; ++m)
            #pragma unroll
            for (int rr = 0; rr < 4; ++rr)
              ac[m][rr] = fmaf(vcur[(rg * 4 + rr) * P_V + i * 3 + m], w, ac[m][rr]);
        }
        #pragma unroll
        for (int rr = 0; rr < 4; ++rr) {
          int r = rg * 4 + rr;
          float b0 = vprev[r * P_V + j0 * 3 + 0];
          float b1 = vprev[r * P_V + j0 * 3 + 1];
          float b2 = vprev[r * P_V + j0 * 3 + 2];
          scr[r * P_SCR + j0 * 3 + 0] = ac[1][rr] * b2 - ac[2][rr] * b1;
          scr[r * P_SCR + j0 * 3 + 1] = ac[2][rr] * b0 - ac[0][rr] * b2;
          scr[r * P_SCR + j0 * 3 + 2] = ac[0][rr] * b1 - ac[1][rr] * b0;
        }
      }
      __syncthreads();
      if (tid < TILE) {
        float p[3];
        #pragma unroll
        for (int m = 0; m < 3; ++m) {
          float s = 0.f;
          for (int j = 0; j < 64; ++j) s += scr[tid * P_SCR + j * 3 + m];
          p[m] = s * P1S;
          st[tid * P_ST + 1 + m] = p[m];
        }
        st[tid * P_ST + 4] = sqrtf(p[0]*p[0] + p[1]*p[1] + p[2]*p[2]);
      }
    } else {
      if (tid < TILE) {
        #pragma unroll
        for (int c = 0; c < 5; ++c) st[tid * P_ST + c] = 0.f;
      }
    }
    __syncthreads();

    // ---- F: s_tilde = cat(161) @ Ws[k] + bs[k] -> Sk ----
    {
      const float* W = Wsm + k * 161 * 256;
      float ac[4][4] = {};
      for (int a = 0; a < 161; ++a) {
        float w0 = W[a * 256 + j0];
        float w1 = W[a * 256 + j0 + 64];
        float w2 = W[a * 256 + j0 + 128];
        float w3 = W[a * 256 + j0 + 192];
        #pragma unroll
        for (int rr = 0; rr < 4; ++rr) {
          float xa = cat[(rg * 4 + rr) * P_CAT + a];
          ac[0][rr] = fmaf(xa, w0, ac[0][rr]);
          ac[1][rr] = fmaf(xa, w1, ac[1][rr]);
          ac[2][rr] = fmaf(xa, w2, ac[2][rr]);
          ac[3][rr] = fmaf(xa, w3, ac[3][rr]);
        }
      }
      #pragma unroll
      for (int t = 0; t < 4; ++t) {
        float bias = bsv[k * 256 + j0 + 64 * t];
        #pragma unroll
        for (int rr = 0; rr < 4; ++rr)
          Sk[(rg * 4 + rr) * P_SK + j0 + 64 * t] = ac[t][rr] + bias;
      }
    }

    // ---- G: v1o[j][m] = sum_i v_k[i][m] Wv1o[i][j] * inv1 ----
    {
      const float* W = Wv1o + k * 64 * 64;
      float ac[3][4] = {};
      #pragma unroll 2
      for (int i = 0; i < 64; ++i) {
        float w = W[i * 64 + j0];
        #pragma unroll
        for (int m = 0; m < 3; ++m)
          #pragma unroll
          for (int rr = 0; rr < 4; ++rr)
            ac[m][rr] = fmaf(vcur[(rg * 4 + rr) * P_V + i * 3 + m], w, ac[m][rr]);
      }
      #pragma unroll
      for (int rr = 0; rr < 4; ++rr)
        #pragma unroll
        for (int m = 0; m < 3; ++m)
          v1o[(rg * 4 + rr) * P_V1O + j0 * 3 + m] = ac[m][rr] * INV1;
    }
    __syncthreads();

    // ---- G2: m vector ----
    for (int idx = tid; idx < TILE * 64; idx += NTHR) {
      int r = idx >> 6, j = idx & 63;
      float a = v1o[r * P_V1O + j * 3];
      float b = v1o[r * P_V1O + j * 3 + 1];
      float c = v1o[r * P_V1O + j * 3 + 2];
      mb[r * P_MB + j] = sqrtf(a*a + b*b + c*c);
    }
    for (int idx = tid; idx < TILE * 64; idx += NTHR) {
      int r = idx >> 6, j = idx & 63;
      mb[r * P_MB + 64 + j] = st[r * P_ST + 4] * fabsf(Wv1e[k * 64 + j]);
    }
    __syncthreads();

    // ---- H: layernorm stats over [Sk(256) | mb(128)] ----
    {
      const int tg = tid & 15, r = tid >> 4;
      float s = 0.f, ss = 0.f;
      for (int c = tg; c < 256; c += 16) { float v = Sk[r * P_SK + c]; s += v; ss = fmaf(v, v, ss); }
      for (int c = tg; c < 128; c += 16) { float v = mb[r * P_MB + c]; s += v; ss = fmaf(v, v, ss); }
      scr[r * P_SCR + tg] = s;
      scr[r * P_SCR + 16 + tg] = ss;
    }
    __syncthreads();
    if (tid < TILE) {
      float s = 0.f, ss = 0.f;
      for (int i = 0; i < 16; ++i) { s += scr[tid * P_SCR + i]; ss += scr[tid * P_SCR + 16 + i]; }
      float mu  = s * (1.f / 384.f);
      float var = ss * (1.f / 384.f) - mu * mu;
      st[tid * P_ST + 5] = mu;
      st[tid * P_ST + 6] = rsqrtf(var + 1e-5f);
    }
    __syncthreads();

    // ---- I: e_k = silu(LN(score) @ Wm1 + bm1) @ Wm2 + bm2 ----
    {
      float acc[4] = {0,0,0,0};
      float muv[4], rsv[4];
      #pragma unroll
      for (int rr = 0; rr < 4; ++rr) {
        muv[rr] = st[(rg * 4 + rr) * P_ST + 5];
        rsv[rr] = st[(rg * 4 + rr) * P_ST + 6];
      }
      for (int f = 0; f < 256; ++f) {
        float w1 = Wm1[f * 64 + j0];
        float gf = gma[f], bf = bta[f];
        #pragma unroll
        for (int rr = 0; rr < 4; ++rr) {
          float val = Sk[(rg * 4 + rr) * P_SK + f];
          float hv = (val - muv[rr]) * rsv[rr] * gf + bf;
          acc[rr] = fmaf(hv, w1, acc[rr]);
        }
      }
      for (int f = 0; f < 128; ++f) {
        float w1 = Wm1[(256 + f) * 64 + j0];
        float gf = gma[256 + f], bf = bta[256 + f];
        #pragma unroll
        for (int rr = 0; rr < 4; ++rr) {
          float val = mb[(rg * 4 + rr) * P_MB + f];
          float hv = (val - muv[rr]) * rsv[rr] * gf + bf;
          acc[rr] = fmaf(hv, w1, acc[rr]);
        }
      }
      float wm2 = Wm2[j0], b1 = bm1[j0], b2 = bm2[0];
      #pragma unroll
      for (int rr = 0; rr < 4; ++rr) {
        float y = acc[rr] + b1;
        float contrib = (y * sigmoidf_(y)) * wm2;
        #pragma unroll
        for (int off = 32; off >= 1; off >>= 1) contrib += __shfl_down(contrib, off);
        if (j0 == 0) st[(rg * 4 + rr) * P_ST + 7] = contrib + b2;
      }
    }
    __syncthreads();

    // ---- J: online-softmax state update ----
    if (tid < TILE) {
      float e = st[tid * P_ST + 7];
      float w, rf, Z, mxn;
      if (k == 0) { mxn = e; w = 1.f; rf = 0.f; Z = 1.f; }
      else {
        float mxo = st[tid * P_ST + 9], Zo = st[tid * P_ST + 8];
        mxn = fmaxf(mxo, e);
        rf = expf(mxo - mxn);
        w  = expf(e - mxn);
        Z  = fmaf(Zo, rf, w);
      }
      st[tid * P_ST + 8]  = Z;  st[tid * P_ST + 9]  = mxn;
      st[tid * P_ST + 10] = w;  st[tid * P_ST + 11] = rf;
    }
    __syncthreads();

    // ---- J2: running numerators ----
    for (int idx = tid; idx < TILE * 256; idx += NTHR) {
      int r = idx >> 8, c = idx & 255;
      float w = st[r * P_ST + 10], rf = st[r * P_ST + 11];
      float nv = w * Sk[r * P_SK + c];
      if (k > 0) nv = fmaf(rf, Nm0[r * P_N0 + c], nv);
      Nm0[r * P_N0 + c] = nv;
    }
    for (int idx = tid; idx < TILE * 384; idx += NTHR) {
      int r = idx / 384, c = idx - r * 384;
      float w = st[r * P_ST + 10], rf = st[r * P_ST + 11];
      float val;
      if (c < 192) {
        val = v1o[r * P_V1O + c];
      } else {
        int cc = c - 192, j = cc / 3, m = cc - j * 3;
        val = st[r * P_ST + 1 + m] * Wv1e[k * 64 + j];
      }
      float nv = w * val;
      if (k > 0) nv = fmaf(rf, Nm1[r * P_N1 + c], nv);
      Nm1[r * P_N1 + c] = nv;
    }
    __syncthreads();
  }

  // ---- output: out0 = Nm0/Z, out1 = Nm1/Z ----
  if (tid < TILE) st[tid * P_ST + 10] = 1.f / st[tid * P_ST + 8];
  __syncthreads();
  for (int idx = tid; idx < TILE * 256; idx += NTHR) {
    int r = idx >> 8, c = idx & 255;
    out[(size_t)(row0 + r) * 256 + c] = Nm0[r * P_N0 + c] * st[r * P_ST + 10];
  }
  const size_t o1 = (size_t)N_ROWS * 256;
  for (int idx = tid; idx < TILE * 384; idx += NTHR) {
    int r = idx / 384, c = idx - r * 384;
    out[o1 + (size_t)(row0 + r) * 384 + c] = Nm1[r * P_N1 + c] * st[r * P_ST + 10];
  }
}

extern "C" void kernel_launch(void* const* d_in, const int* in_sizes, int n_in,
                              void* d_out, int out_size, void* d_ws, size_t ws_size,
                              hipStream_t stream) {
  const float* x0   = (const float*)d_in[0];
  const float* x1   = (const float*)d_in[1];
  const float* x2   = (const float*)d_in[2];
  const float* x3   = (const float*)d_in[3];
  const float* Wl0  = (const float*)d_in[4];
  const float* Wl1  = (const float*)d_in[5];
  const float* Wl2  = (const float*)d_in[6];
  const float* Wtp0 = (const float*)d_in[7];
  const float* Wtp1 = (const float*)d_in[8];
  const float* Wsm  = (const float*)d_in[9];
  const float* bsv  = (const float*)d_in[10];
  const float* Wv1o = (const float*)d_in[11];
  const float* Wv1e = (const float*)d_in[12];
  const float* gma  = (const float*)d_in[13];
  const float* bta  = (const float*)d_in[14];
  const float* Wm1  = (const float*)d_in[15];
  const float* bm1  = (const float*)d_in[16];
  const float* Wm2  = (const float*)d_in[17];
  const float* bm2  = (const float*)d_in[18];
  float* out = (float*)d_out;

  // allow >64KB dynamic LDS (gfx950 has 160 KiB/CU); ignore error if a no-op
  (void)hipFuncSetAttribute(reinterpret_cast<const void*>(efb_kernel),
                            hipFuncAttributeMaxDynamicSharedMemorySize, SMEM_BYTES);

  dim3 grid(N_ROWS / TILE), block(NTHR);
  efb_kernel<<<grid, block, SMEM_BYTES, stream>>>(
      x0, x1, x2, x3, Wl0, Wl1, Wl2, Wtp0, Wtp1, Wsm, bsv,
      Wv1o, Wv1e, gma, bta, Wm1, bm1, Wm2, bm2, out);
}

// Round 2
// 4559.503 us; speedup vs baseline: 2.6613x; 2.6613x over previous
//
#include <hip/hip_runtime.h>
#include <math.h>

#define NTHR 64
#define ROWS 8
#define N_ROWS 80000
#define PU 488   // union region: x row (480) / Sk(0..255)+mb(260..387)
#define PC 164   // cat: s_k(128) | n_k(32) | p0 @160
#define PV 196   // v_k: j*3+m (192)

__device__ __forceinline__ float wsum64(float v) {
  #pragma unroll
  for (int m = 1; m < 64; m <<= 1) v += __shfl_xor(v, m, 64);
  return v;
}

// acc[m][r] += sum_i lds[r][off + i*3+m] * W[i*64 + j0]   (i = 0..63)
__device__ __forceinline__ void contract64(const float* __restrict__ W, int j0,
                                           const float* lds, int pitch, int off,
                                           float acc[3][ROWS]) {
  #pragma unroll 2
  for (int ic = 0; ic < 16; ++ic) {
    float wt[4];
    #pragma unroll
    for (int ii = 0; ii < 4; ++ii) wt[ii] = W[(ic * 4 + ii) * 64 + j0];
    #pragma unroll
    for (int r = 0; r < ROWS; ++r) {
      const float* p = lds + r * pitch + off + ic * 12;
      float4 q0 = *(const float4*)p;
      float4 q1 = *(const float4*)(p + 4);
      float4 q2 = *(const float4*)(p + 8);
      float xv[12] = {q0.x,q0.y,q0.z,q0.w, q1.x,q1.y,q1.z,q1.w, q2.x,q2.y,q2.z,q2.w};
      #pragma unroll
      for (int ii = 0; ii < 4; ++ii)
        #pragma unroll
        for (int m = 0; m < 3; ++m)
          acc[m][r] = fmaf(xv[ii * 3 + m], wt[ii], acc[m][r]);
    }
  }
}

__global__ __launch_bounds__(NTHR, 2)
void efb_kernel(const float* __restrict__ x0, const float* __restrict__ x1,
                const float* __restrict__ x2, const float* __restrict__ x3,
                const float* __restrict__ Wl0, const float* __restrict__ Wl1,
                const float* __restrict__ Wl2, const float* __restrict__ Wtp0,
                const float* __restrict__ Wtp1, const float* __restrict__ Wsm,
                const float* __restrict__ bsv, const float* __restrict__ Wv1o,
                const float* __restrict__ Wv1e, const float* __restrict__ gma,
                const float* __restrict__ bta, const float* __restrict__ Wm1,
                const float* __restrict__ bm1, const float* __restrict__ Wm2,
                const float* __restrict__ bm2, float* __restrict__ out)
{
  __shared__ float U[ROWS * PU];
  __shared__ float cat[ROWS * PC];
  __shared__ float vbuf[ROWS * PV];

  const int lane = threadIdx.x;      // 64 lanes = feature columns
  const int j0 = lane;
  const int j2 = lane & 31, half = lane >> 5;   // stage D mapping
  const int row0 = blockIdx.x * ROWS;

  const float INV0 = 0.08838834764831845f;   // 1/sqrt(128)
  const float INV1 = 0.125f;                 // 1/sqrt(64)
  const float INV2 = 0.17677669529663687f;   // 1/sqrt(32)
  const float P0S  = 0.009021097956087907f;  // 1/(sqrt(3)*64)
  const float P1S  = 0.011048543456039806f;  // 1/(sqrt(2)*64)

  // persistent per-lane state
  float Nm0[4][ROWS];     // softmax numerator for S (cols j0+64t)
  float vnum[3][ROWS];    // numerator for v1o part (col j0, 3 comps)
  float ne[3][ROWS];      // numerator for v1e part (col j0)
  float vpr[3][ROWS];     // v_{k-1}[r][j0][m]
  float mx[ROWS], Zz[ROWS];
  #pragma unroll
  for (int r = 0; r < ROWS; ++r) {
    mx[r] = -1e30f; Zz[r] = 0.f;
    #pragma unroll
    for (int t = 0; t < 4; ++t) Nm0[t][r] = 0.f;
    #pragma unroll
    for (int m = 0; m < 3; ++m) { vnum[m][r] = 0.f; ne[m][r] = 0.f; vpr[m][r] = 0.f; }
  }

  for (int k = 0; k < 4; ++k) {
    const float* gx = (k == 0) ? x0 : (k == 1) ? x1 : (k == 2) ? x2 : x3;
    gx += (size_t)row0 * 480;

    __syncthreads();   // prior k's broadcast reads of U done before rewrite
    // ---- A: stage x tile ----
    #pragma unroll
    for (int r = 0; r < ROWS; ++r)
      for (int c = lane; c < 120; c += 64) {
        float4 q = ((const float4*)gx)[r * 120 + c];
        *(float4*)&U[r * PU + c * 4] = q;
      }
    __syncthreads();

    // ---- B: s_k = x_s @ Wl0[k] * INV0 -> cat[0:128] ----
    {
      const float* W = Wl0 + k * 16384;
      float a0[ROWS] = {}, a1[ROWS] = {};
      #pragma unroll 2
      for (int ic = 0; ic < 32; ++ic) {
        float wt0[4], wt1[4];
        #pragma unroll
        for (int ii = 0; ii < 4; ++ii) {
          wt0[ii] = W[(ic * 4 + ii) * 128 + j0];
          wt1[ii] = W[(ic * 4 + ii) * 128 + 64 + j0];
        }
        #pragma unroll
        for (int r = 0; r < ROWS; ++r) {
          float4 q = *(const float4*)&U[r * PU + ic * 4];
          float xv[4] = {q.x, q.y, q.z, q.w};
          #pragma unroll
          for (int ii = 0; ii < 4; ++ii) {
            a0[r] = fmaf(xv[ii], wt0[ii], a0[r]);
            a1[r] = fmaf(xv[ii], wt1[ii], a1[r]);
          }
        }
      }
      #pragma unroll
      for (int r = 0; r < ROWS; ++r) {
        cat[r * PC + j0]      = a0[r] * INV0;
        cat[r * PC + 64 + j0] = a1[r] * INV0;
      }
    }

    // ---- C: v_k[r][j0][m] ----
    float vtmp[3][ROWS];
    {
      float ac[3][ROWS] = {};
      contract64(Wl1 + k * 4096, j0, U, PU, 128, ac);
      #pragma unroll
      for (int r = 0; r < ROWS; ++r)
        #pragma unroll
        for (int m = 0; m < 3; ++m) {
          vtmp[m][r] = ac[m][r] * INV1;
          vbuf[r * PV + j0 * 3 + m] = vtmp[m][r];
        }
    }

    // ---- D: n_k -> cat[128:160] ----
    {
      const float* W = Wl2 + k * 1024;
      float t5[5][4] = {};
      #pragma unroll 2
      for (int ic = 0; ic < 8; ++ic) {
        float wt[4];
        #pragma unroll
        for (int ii = 0; ii < 4; ++ii) wt[ii] = W[(ic * 4 + ii) * 32 + j2];
        #pragma unroll
        for (int rr = 0; rr < 4; ++rr) {
          const float* p = &U[(half * 4 + rr) * PU + 320 + ic * 20];
          float xt[20];
          #pragma unroll
          for (int q4 = 0; q4 < 5; ++q4) {
            float4 q = *(const float4*)(p + q4 * 4);
            xt[q4*4] = q.x; xt[q4*4+1] = q.y; xt[q4*4+2] = q.z; xt[q4*4+3] = q.w;
          }
          #pragma unroll
          for (int ii = 0; ii < 4; ++ii)
            #pragma unroll
            for (int m = 0; m < 5; ++m)
              t5[m][rr] = fmaf(xt[ii * 5 + m], wt[ii], t5[m][rr]);
        }
      }
      #pragma unroll
      for (int rr = 0; rr < 4; ++rr) {
        float s = 0.f;
        #pragma unroll
        for (int m = 0; m < 5; ++m) { float tt = t5[m][rr] * INV2; s = fmaf(tt, tt, s); }
        cat[(half * 4 + rr) * PC + 128 + j2] = sqrtf(s);
      }
    }
    __syncthreads();

    // ---- E: p0, p1 ----
    float p1[3][ROWS], np1[ROWS];
    if (k > 0) {
      {
        float u0[3][ROWS] = {};
        contract64(Wtp0, j0, vbuf, PV, 0, u0);
        #pragma unroll
        for (int r = 0; r < ROWS; ++r) {
          float s = 0.f;
          #pragma unroll
          for (int m = 0; m < 3; ++m) s = fmaf(u0[m][r], vpr[m][r], s);
          s = wsum64(s) * P0S;
          if (lane == r) cat[r * PC + 160] = s;
        }
      }
      {
        float u1[3][ROWS] = {};
        contract64(Wtp1, j0, vbuf, PV, 0, u1);
        #pragma unroll
        for (int r = 0; r < ROWS; ++r) {
          float c0 = u1[1][r] * vpr[2][r] - u1[2][r] * vpr[1][r];
          float c1 = u1[2][r] * vpr[0][r] - u1[0][r] * vpr[2][r];
          float c2 = u1[0][r] * vpr[1][r] - u1[1][r] * vpr[0][r];
          p1[0][r] = wsum64(c0) * P1S;
          p1[1][r] = wsum64(c1) * P1S;
          p1[2][r] = wsum64(c2) * P1S;
          np1[r] = sqrtf(p1[0][r]*p1[0][r] + p1[1][r]*p1[1][r] + p1[2][r]*p1[2][r]);
        }
      }
    } else {
      #pragma unroll
      for (int r = 0; r < ROWS; ++r) {
        #pragma unroll
        for (int m = 0; m < 3; ++m) p1[m][r] = 0.f;
        np1[r] = 0.f;
        if (lane == r) cat[r * PC + 160] = 0.f;
      }
    }
    // v_prev <- v_k
    #pragma unroll
    for (int r = 0; r < ROWS; ++r)
      #pragma unroll
      for (int m = 0; m < 3; ++m) vpr[m][r] = vtmp[m][r];
    __syncthreads();

    // ---- F: s_tilde -> U[0:256] (Sk) ----
    {
      const float* W = Wsm + k * 41216;
      float ac4[4][ROWS] = {};
      #pragma unroll 1
      for (int ic = 0; ic < 40; ++ic) {
        float w4[4][4];
        #pragma unroll
        for (int ii = 0; ii < 4; ++ii)
          #pragma unroll
          for (int t = 0; t < 4; ++t) w4[ii][t] = W[(ic * 4 + ii) * 256 + t * 64 + j0];
        #pragma unroll
        for (int r = 0; r < ROWS; ++r) {
          float4 q = *(const float4*)&cat[r * PC + ic * 4];
          float cv[4] = {q.x, q.y, q.z, q.w};
          #pragma unroll
          for (int ii = 0; ii < 4; ++ii)
            #pragma unroll
            for (int t = 0; t < 4; ++t)
              ac4[t][r] = fmaf(cv[ii], w4[ii][t], ac4[t][r]);
        }
      }
      { // a = 160 (p0 term)
        float w4[4];
        #pragma unroll
        for (int t = 0; t < 4; ++t) w4[t] = W[160 * 256 + t * 64 + j0];
        #pragma unroll
        for (int r = 0; r < ROWS; ++r) {
          float c = cat[r * PC + 160];
          #pragma unroll
          for (int t = 0; t < 4; ++t) ac4[t][r] = fmaf(c, w4[t], ac4[t][r]);
        }
      }
      float bt[4];
      #pragma unroll
      for (int t = 0; t < 4; ++t) bt[t] = bsv[k * 256 + t * 64 + j0];
      #pragma unroll
      for (int r = 0; r < ROWS; ++r)
        #pragma unroll
        for (int t = 0; t < 4; ++t)
          U[r * PU + t * 64 + j0] = ac4[t][r] + bt[t];
    }

    // ---- G: v1o + mb ----
    float vo[3][ROWS], mbS[ROWS], mbE[ROWS];
    float wv = Wv1e[k * 64 + j0];
    {
      float ac[3][ROWS] = {};
      contract64(Wv1o + k * 4096, j0, vbuf, PV, 0, ac);
      float awv = fabsf(wv);
      #pragma unroll
      for (int r = 0; r < ROWS; ++r) {
        float s = 0.f;
        #pragma unroll
        for (int m = 0; m < 3; ++m) { vo[m][r] = ac[m][r] * INV1; s = fmaf(vo[m][r], vo[m][r], s); }
        mbS[r] = sqrtf(s);
        mbE[r] = np1[r] * awv;
        U[r * PU + 260 + j0] = mbS[r];
        U[r * PU + 260 + 64 + j0] = mbE[r];
      }
    }
    __syncthreads();

    // ---- H: layernorm stats ----
    float mu8[ROWS], rs8[ROWS];
    #pragma unroll
    for (int r = 0; r < ROWS; ++r) {
      float s = 0.f, sq = 0.f;
      #pragma unroll
      for (int t = 0; t < 4; ++t) {
        float v = U[r * PU + t * 64 + j0];
        s += v; sq = fmaf(v, v, sq);
      }
      s += mbS[r] + mbE[r];
      sq = fmaf(mbS[r], mbS[r], sq); sq = fmaf(mbE[r], mbE[r], sq);
      s = wsum64(s); sq = wsum64(sq);
      mu8[r] = s * (1.f / 384.f);
      float var = sq * (1.f / 384.f) - mu8[r] * mu8[r];
      rs8[r] = rsqrtf(var + 1e-5f);
    }

    // ---- I: e_k ----
    float E8[ROWS];
    {
      float A8[ROWS] = {};
      float B0 = 0.f, C0 = 0.f;
      #pragma unroll 2
      for (int ic = 0; ic < 64; ++ic) {
        float wv4[4], gv4[4], bv4[4];
        #pragma unroll
        for (int ii = 0; ii < 4; ++ii) {
          int f = ic * 4 + ii;
          wv4[ii] = Wm1[f * 64 + j0]; gv4[ii] = gma[f]; bv4[ii] = bta[f];
        }
        float gw[4];
        #pragma unroll
        for (int ii = 0; ii < 4; ++ii) {
          gw[ii] = gv4[ii] * wv4[ii];
          B0 += gw[ii];
          C0 = fmaf(bv4[ii], wv4[ii], C0);
        }
        #pragma unroll
        for (int r = 0; r < ROWS; ++r) {
          float4 q = *(const float4*)&U[r * PU + ic * 4];
          float xv[4] = {q.x, q.y, q.z, q.w};
          #pragma unroll
          for (int ii = 0; ii < 4; ++ii) A8[r] = fmaf(xv[ii], gw[ii], A8[r]);
        }
      }
      #pragma unroll 2
      for (int ic = 0; ic < 32; ++ic) {
        float wv4[4], gv4[4], bv4[4];
        #pragma unroll
        for (int ii = 0; ii < 4; ++ii) {
          int f = 256 + ic * 4 + ii;
          wv4[ii] = Wm1[f * 64 + j0]; gv4[ii] = gma[f]; bv4[ii] = bta[f];
        }
        float gw[4];
        #pragma unroll
        for (int ii = 0; ii < 4; ++ii) {
          gw[ii] = gv4[ii] * wv4[ii];
          B0 += gw[ii];
          C0 = fmaf(bv4[ii], wv4[ii], C0);
        }
        #pragma unroll
        for (int r = 0; r < ROWS; ++r) {
          float4 q = *(const float4*)&U[r * PU + 260 + ic * 4];
          float xv[4] = {q.x, q.y, q.z, q.w};
          #pragma unroll
          for (int ii = 0; ii < 4; ++ii) A8[r] = fmaf(xv[ii], gw[ii], A8[r]);
        }
      }
      float b1 = bm1[j0], w2 = Wm2[j0], b2v = bm2[0];
      #pragma unroll
      for (int r = 0; r < ROWS; ++r) {
        float y = rs8[r] * (A8[r] - mu8[r] * B0) + C0 + b1;
        float sl = y / (1.f + expf(-y));
        E8[r] = wsum64(sl * w2) + b2v;
      }
    }

    // ---- J: online softmax update ----
    #pragma unroll
    for (int r = 0; r < ROWS; ++r) {
      float mxn = fmaxf(mx[r], E8[r]);
      float rf = expf(mx[r] - mxn);
      float w = expf(E8[r] - mxn);
      Zz[r] = Zz[r] * rf + w;
      mx[r] = mxn;
      #pragma unroll
      for (int t = 0; t < 4; ++t) {
        float skv = U[r * PU + t * 64 + j0];
        Nm0[t][r] = fmaf(Nm0[t][r], rf, w * skv);
      }
      #pragma unroll
      for (int m = 0; m < 3; ++m) {
        vnum[m][r] = fmaf(vnum[m][r], rf, w * vo[m][r]);
        ne[m][r]   = fmaf(ne[m][r],   rf, w * (p1[m][r] * wv));
      }
    }
  }

  // ---- epilogue ----
  __syncthreads();
  float iz[ROWS];
  #pragma unroll
  for (int r = 0; r < ROWS; ++r) iz[r] = 1.f / Zz[r];
  #pragma unroll
  for (int r = 0; r < ROWS; ++r)
    #pragma unroll
    for (int t = 0; t < 4; ++t)
      out[(size_t)(row0 + r) * 256 + t * 64 + j0] = Nm0[t][r] * iz[r];
  #pragma unroll
  for (int r = 0; r < ROWS; ++r)
    #pragma unroll
    for (int m = 0; m < 3; ++m) {
      U[r * PU + j0 * 3 + m]       = vnum[m][r] * iz[r];
      U[r * PU + 192 + j0 * 3 + m] = ne[m][r] * iz[r];
    }
  __syncthreads();
  const size_t o1 = (size_t)N_ROWS * 256;
  #pragma unroll
  for (int r = 0; r < ROWS; ++r)
    for (int c = lane; c < 96; c += 64) {
      float4 q = *(const float4*)&U[r * PU + c * 4];
      *(float4*)&out[o1 + (size_t)(row0 + r) * 384 + c * 4] = q;
    }
}

extern "C" void kernel_launch(void* const* d_in, const int* in_sizes, int n_in,
                              void* d_out, int out_size, void* d_ws, size_t ws_size,
                              hipStream_t stream) {
  const float* x0   = (const float*)d_in[0];
  const float* x1   = (const float*)d_in[1];
  const float* x2   = (const float*)d_in[2];
  const float* x3   = (const float*)d_in[3];
  const float* Wl0  = (const float*)d_in[4];
  const float* Wl1  = (const float*)d_in[5];
  const float* Wl2  = (const float*)d_in[6];
  const float* Wtp0 = (const float*)d_in[7];
  const float* Wtp1 = (const float*)d_in[8];
  const float* Wsm  = (const float*)d_in[9];
  const float* bsv  = (const float*)d_in[10];
  const float* Wv1o = (const float*)d_in[11];
  const float* Wv1e = (const float*)d_in[12];
  const float* gma  = (const float*)d_in[13];
  const float* bta  = (const float*)d_in[14];
  const float* Wm1  = (const float*)d_in[15];
  const float* bm1  = (const float*)d_in[16];
  const float* Wm2  = (const float*)d_in[17];
  const float* bm2  = (const float*)d_in[18];
  float* out = (float*)d_out;

  dim3 grid(N_ROWS / ROWS), block(NTHR);
  efb_kernel<<<grid, block, 0, stream>>>(
      x0, x1, x2, x3, Wl0, Wl1, Wl2, Wtp0, Wtp1, Wsm, bsv,
      Wv1o, Wv1e, gma, bta, Wm1, bm1, Wm2, bm2, out);
}